// Round 1
// baseline (2895.086 us; speedup 1.0000x reference)
//
#include <hip/hip_runtime.h>

#define DD 128

// ---------------------------------------------------------------------------
// k_init_xi: Xi = a * X0   (Xi lives in d_out; fully overwrites poison)
// ---------------------------------------------------------------------------
__global__ __launch_bounds__(256)
void k_init_xi(const float* __restrict__ X0, const float* __restrict__ alphaP,
               float* __restrict__ Xi, int n4) {
    int gid = blockIdx.x * 256 + threadIdx.x;
    if (gid >= n4) return;
    const float a = alphaP[0];
    float4 x = ((const float4*)X0)[gid];
    float4 o;
    o.x = a * x.x; o.y = a * x.y; o.z = a * x.z; o.w = a * x.w;
    ((float4*)Xi)[gid] = o;
}

// ---------------------------------------------------------------------------
// k_scatter_edge: Xe[g1_dst] += X[g1_src]    (raw segment sum, fp32 atomics)
// 32 threads per nnz, 4 floats each (float4 gather + 4 atomic adds)
// ---------------------------------------------------------------------------
__global__ __launch_bounds__(256)
void k_scatter_edge(const float* __restrict__ X, const int* __restrict__ src,
                    const int* __restrict__ dst, float* __restrict__ Xe, int nnz) {
    int gid = blockIdx.x * 256 + threadIdx.x;
    int i = gid >> 5;
    if (i >= nnz) return;
    int k = (gid & 31) << 2;
    int s = src[i];
    int d = dst[i];
    float4 v = *(const float4*)(X + (size_t)s * DD + k);
    float* p = Xe + (size_t)d * DD + k;
    unsafeAtomicAdd(p + 0, v.x);
    unsafeAtomicAdd(p + 1, v.y);
    unsafeAtomicAdd(p + 2, v.z);
    unsafeAtomicAdd(p + 3, v.w);
}

// ---------------------------------------------------------------------------
// k_scatter_node: Xi[g2_dst] += (1-a)*degV[g2_dst]*degE[g2_src] * Xe[g2_src]
// (folds the degE edge scale, degV node scale, and (1-a) residual blend)
// ---------------------------------------------------------------------------
__global__ __launch_bounds__(256)
void k_scatter_node(const float* __restrict__ Xe, const int* __restrict__ src,
                    const int* __restrict__ dst, const float* __restrict__ degE,
                    const float* __restrict__ degV, const float* __restrict__ alphaP,
                    float* __restrict__ Xi, int nnz) {
    int gid = blockIdx.x * 256 + threadIdx.x;
    int i = gid >> 5;
    if (i >= nnz) return;
    int k = (gid & 31) << 2;
    int s = src[i];
    int d = dst[i];
    float f = (1.0f - alphaP[0]) * degV[d] * degE[s];
    float4 v = *(const float4*)(Xe + (size_t)s * DD + k);
    float* p = Xi + (size_t)d * DD + k;
    unsafeAtomicAdd(p + 0, f * v.x);
    unsafeAtomicAdd(p + 1, f * v.y);
    unsafeAtomicAdd(p + 2, f * v.z);
    unsafeAtomicAdd(p + 3, f * v.w);
}

// ---------------------------------------------------------------------------
// k_gemm: out = (1-b)*Xi + b * (Xi @ W^T), in place (xio = Xi = out).
// W transposed into 64 KB static LDS (Wt[d][c] = W[c][d]); each thread owns a
// 4-row x 4-col output tile; Xi rows come in as uniform-address global loads
// (L1 broadcast). In-place is safe: each row is read and written by exactly
// one half-wave, and stores follow all loads in program order.
// ---------------------------------------------------------------------------
#define ROWFMA(acc, xv)                                           \
    acc.x += xv.x*w0.x + xv.y*w1.x + xv.z*w2.x + xv.w*w3.x;       \
    acc.y += xv.x*w0.y + xv.y*w1.y + xv.z*w2.y + xv.w*w3.y;       \
    acc.z += xv.x*w0.z + xv.y*w1.z + xv.z*w2.z + xv.w*w3.z;       \
    acc.w += xv.x*w0.w + xv.y*w1.w + xv.z*w2.w + xv.w*w3.w;

__global__ __launch_bounds__(256, 2)
void k_gemm(float* xio, const float* __restrict__ W,
            const float* __restrict__ betaP, int n_rows) {
    __shared__ float Wt[DD * DD];   // 64 KB: Wt[d*128 + c] = W[c*128 + d]
    const int tid = threadIdx.x;

    // Cooperative transpose-load of W. Thread reads 4x4 micro-tiles along d
    // (float4 rows), transposes in registers, writes c-contiguous float4 to
    // LDS -> conflict-free ds_write_b128.
    {
        int c = (tid & 31) << 2;
        int dsel = tid >> 5;               // 0..7
        for (int p = 0; p < 4; ++p) {
            int d = ((p << 3) + dsel) << 2;  // 0..124 step 4
            float4 r0 = *(const float4*)(W + (c + 0) * DD + d);
            float4 r1 = *(const float4*)(W + (c + 1) * DD + d);
            float4 r2 = *(const float4*)(W + (c + 2) * DD + d);
            float4 r3 = *(const float4*)(W + (c + 3) * DD + d);
            *(float4*)(Wt + (d + 0) * DD + c) = make_float4(r0.x, r1.x, r2.x, r3.x);
            *(float4*)(Wt + (d + 1) * DD + c) = make_float4(r0.y, r1.y, r2.y, r3.y);
            *(float4*)(Wt + (d + 2) * DD + c) = make_float4(r0.z, r1.z, r2.z, r3.z);
            *(float4*)(Wt + (d + 3) * DD + c) = make_float4(r0.w, r1.w, r2.w, r3.w);
        }
    }
    __syncthreads();

    const float b  = betaP[0];
    const float ib = 1.0f - b;
    const int t4 = (tid & 31) << 2;     // this thread's column base (c..c+3)
    const int rg = tid >> 5;            // row group 0..7 -> rows rg*4..rg*4+3
    const int ntiles = n_rows >> 5;     // 32 rows per tile (100000/32 = 3125)

    for (int tile = blockIdx.x; tile < ntiles; tile += gridDim.x) {
        const int row0 = (tile << 5) + (rg << 2);
        const float* xr = xio + (size_t)row0 * DD;
        float4 a0 = {0,0,0,0}, a1 = {0,0,0,0}, a2 = {0,0,0,0}, a3 = {0,0,0,0};
        #pragma unroll 8
        for (int d = 0; d < DD; d += 4) {
            float4 w0 = *(const float4*)(Wt + (d + 0) * DD + t4);
            float4 w1 = *(const float4*)(Wt + (d + 1) * DD + t4);
            float4 w2 = *(const float4*)(Wt + (d + 2) * DD + t4);
            float4 w3 = *(const float4*)(Wt + (d + 3) * DD + t4);
            float4 x0 = *(const float4*)(xr + 0 * DD + d);
            float4 x1 = *(const float4*)(xr + 1 * DD + d);
            float4 x2 = *(const float4*)(xr + 2 * DD + d);
            float4 x3 = *(const float4*)(xr + 3 * DD + d);
            ROWFMA(a0, x0)
            ROWFMA(a1, x1)
            ROWFMA(a2, x2)
            ROWFMA(a3, x3)
        }
        // epilogue: out = (1-b)*Xi + b*acc  (in place)
        {
            float4 e0 = *(const float4*)(xr + 0 * DD + t4);
            float4 e1 = *(const float4*)(xr + 1 * DD + t4);
            float4 e2 = *(const float4*)(xr + 2 * DD + t4);
            float4 e3 = *(const float4*)(xr + 3 * DD + t4);
            float4 o;
            float* wr = xio + (size_t)row0 * DD;
            o.x = ib*e0.x + b*a0.x; o.y = ib*e0.y + b*a0.y;
            o.z = ib*e0.z + b*a0.z; o.w = ib*e0.w + b*a0.w;
            *(float4*)(wr + 0 * DD + t4) = o;
            o.x = ib*e1.x + b*a1.x; o.y = ib*e1.y + b*a1.y;
            o.z = ib*e1.z + b*a1.z; o.w = ib*e1.w + b*a1.w;
            *(float4*)(wr + 1 * DD + t4) = o;
            o.x = ib*e2.x + b*a2.x; o.y = ib*e2.y + b*a2.y;
            o.z = ib*e2.z + b*a2.z; o.w = ib*e2.w + b*a2.w;
            *(float4*)(wr + 2 * DD + t4) = o;
            o.x = ib*e3.x + b*a3.x; o.y = ib*e3.y + b*a3.y;
            o.z = ib*e3.z + b*a3.z; o.w = ib*e3.w + b*a3.w;
            *(float4*)(wr + 3 * DD + t4) = o;
        }
    }
}

// ---------------------------------------------------------------------------
extern "C" void kernel_launch(void* const* d_in, const int* in_sizes, int n_in,
                              void* d_out, int out_size, void* d_ws, size_t ws_size,
                              hipStream_t stream) {
    const float* X     = (const float*)d_in[0];
    const float* X0    = (const float*)d_in[1];
    const float* degE  = (const float*)d_in[2];
    const float* degV  = (const float*)d_in[3];
    const float* alpha = (const float*)d_in[4];
    const float* beta  = (const float*)d_in[5];
    const float* W     = (const float*)d_in[6];
    const int*   g1s   = (const int*)d_in[7];
    const int*   g1d   = (const int*)d_in[8];
    const int*   g2s   = (const int*)d_in[9];
    const int*   g2d   = (const int*)d_in[10];
    float* out = (float*)d_out;

    const int n_nodes = in_sizes[0] / DD;   // 100000
    const int n_edges = in_sizes[2];        // 20000
    const int nnz     = in_sizes[7];        // 800000

    float* Xe = (float*)d_ws;               // [E,128] scratch, 10.24 MB

    // zero the edge accumulator (d_ws is poisoned each call)
    hipMemsetAsync(Xe, 0, (size_t)n_edges * DD * sizeof(float), stream);

    // Xi (in d_out) = a * X0
    int n4 = n_nodes * (DD / 4);
    k_init_xi<<<(n4 + 255) / 256, 256, 0, stream>>>(X0, alpha, out, n4);

    // Xe[g1_dst] += X[g1_src]
    int sthreads = nnz * 32;
    k_scatter_edge<<<(sthreads + 255) / 256, 256, 0, stream>>>(X, g1s, g1d, Xe, nnz);

    // Xi[g2_dst] += (1-a)*degV[dst]*degE[src] * Xe[g2_src]
    k_scatter_node<<<(sthreads + 255) / 256, 256, 0, stream>>>(Xe, g2s, g2d, degE,
                                                               degV, alpha, out, nnz);

    // out = (1-b)*Xi + b*(Xi @ W^T), in place
    k_gemm<<<512, 256, 0, stream>>>(out, W, beta, n_nodes);
}

// Round 2
// 533.805 us; speedup vs baseline: 5.4235x; 5.4235x over previous
//
#include <hip/hip_runtime.h>

#define DD 128
#define SCAN_CHUNK 2048   // 256 threads x 8 elements per scan block

// ---------------------------------------------------------------------------
// CSR build: histogram -> exclusive scan (3-kernel) -> fill slots
// ---------------------------------------------------------------------------
__global__ __launch_bounds__(256)
void k_hist(const int* __restrict__ dst, int* __restrict__ cnt, int nnz) {
    int i = blockIdx.x * 256 + threadIdx.x;
    if (i < nnz) atomicAdd(&cnt[dst[i]], 1);
}

__global__ __launch_bounds__(256)
void k_scan_blocks(const int* __restrict__ cnt, int* __restrict__ off,
                   int* __restrict__ bsum, int n) {
    __shared__ int sh[256];
    const int tid = threadIdx.x;
    const int base = blockIdx.x * SCAN_CHUNK + tid * 8;
    int v[8];
    int s = 0;
    #pragma unroll
    for (int j = 0; j < 8; ++j) {
        int idx = base + j;
        v[j] = (idx < n) ? cnt[idx] : 0;
        s += v[j];
    }
    sh[tid] = s;
    __syncthreads();
    for (int d = 1; d < 256; d <<= 1) {
        int y = (tid >= d) ? sh[tid - d] : 0;
        __syncthreads();
        sh[tid] += y;
        __syncthreads();
    }
    int incl = sh[tid];
    int run = incl - s;           // exclusive prefix for this thread's chunk
    #pragma unroll
    for (int j = 0; j < 8; ++j) {
        int idx = base + j;
        if (idx < n) off[idx] = run;
        run += v[j];
    }
    if (tid == 255) bsum[blockIdx.x] = incl;   // block total
}

__global__ void k_scan_top(int* __restrict__ bsum, int nb) {
    if (threadIdx.x == 0 && blockIdx.x == 0) {
        int run = 0;
        for (int i = 0; i < nb; ++i) { int t = bsum[i]; bsum[i] = run; run += t; }
    }
}

__global__ __launch_bounds__(256)
void k_scan_add(int* __restrict__ off, const int* __restrict__ bsum,
                int n, int total) {
    int gid = blockIdx.x * 256 + threadIdx.x;
    if (gid < n) off[gid] += bsum[gid >> 11];   // SCAN_CHUNK == 2048
    if (gid == 0) off[n] = total;
}

__global__ __launch_bounds__(256)
void k_fill(const int* __restrict__ dst, const int* __restrict__ src,
            const int* __restrict__ off, int* __restrict__ cur,
            int* __restrict__ srcs, int nnz) {
    int i = blockIdx.x * 256 + threadIdx.x;
    if (i >= nnz) return;
    int d = dst[i];
    int p = atomicAdd(&cur[d], 1);
    srcs[off[d] + p] = src[i];
}

// ---------------------------------------------------------------------------
// k_edge_gather: Xe[e] = degE[e] * sum_{j in seg(e)} X[srcs1[j]]
// half-wave (32 lanes) per edge row; float4 per lane.
// ---------------------------------------------------------------------------
__global__ __launch_bounds__(256)
void k_edge_gather(const float* __restrict__ X, const int* __restrict__ off,
                   const int* __restrict__ srcs, const float* __restrict__ degE,
                   float* __restrict__ Xe, int n_edges) {
    int gid = blockIdx.x * 256 + threadIdx.x;
    int e = gid >> 5;
    if (e >= n_edges) return;
    int k = (gid & 31) << 2;
    int beg = off[e], end = off[e + 1];
    float4 acc = {0, 0, 0, 0};
    for (int j = beg; j < end; ++j) {
        int s = srcs[j];
        float4 v = *(const float4*)(X + (size_t)s * DD + k);
        acc.x += v.x; acc.y += v.y; acc.z += v.z; acc.w += v.w;
    }
    float f = degE[e];
    float4 o;
    o.x = f * acc.x; o.y = f * acc.y; o.z = f * acc.z; o.w = f * acc.w;
    *(float4*)(Xe + (size_t)e * DD + k) = o;
}

// ---------------------------------------------------------------------------
// k_node_gather: Xi[v] = (1-a)*degV[v] * sum_{j in seg(v)} Xe[srcs2[j]] + a*X0[v]
// writes Xi into d_out (every node row fully written).
// ---------------------------------------------------------------------------
__global__ __launch_bounds__(256)
void k_node_gather(const float* __restrict__ Xe, const int* __restrict__ off,
                   const int* __restrict__ srcs, const float* __restrict__ degV,
                   const float* __restrict__ X0, const float* __restrict__ alphaP,
                   float* __restrict__ Xi, int n_nodes) {
    int gid = blockIdx.x * 256 + threadIdx.x;
    int v = gid >> 5;
    if (v >= n_nodes) return;
    int k = (gid & 31) << 2;
    int beg = off[v], end = off[v + 1];
    float4 acc = {0, 0, 0, 0};
    for (int j = beg; j < end; ++j) {
        int s = srcs[j];
        float4 x = *(const float4*)(Xe + (size_t)s * DD + k);
        acc.x += x.x; acc.y += x.y; acc.z += x.z; acc.w += x.w;
    }
    float a = alphaP[0];
    float f = (1.0f - a) * degV[v];
    float4 x0 = *(const float4*)(X0 + (size_t)v * DD + k);
    float4 o;
    o.x = f * acc.x + a * x0.x;
    o.y = f * acc.y + a * x0.y;
    o.z = f * acc.z + a * x0.z;
    o.w = f * acc.w + a * x0.w;
    *(float4*)(Xi + (size_t)v * DD + k) = o;
}

// ---------------------------------------------------------------------------
// k_gemm: out = (1-b)*Xi + b * (Xi @ W^T), in place (xio = Xi = out).
// W transposed into 64 KB static LDS; 4x4 register tile per thread.
// In-place safe: each row read/written only by one half-wave (program order).
// ---------------------------------------------------------------------------
#define ROWFMA(acc, xv)                                           \
    acc.x += xv.x*w0.x + xv.y*w1.x + xv.z*w2.x + xv.w*w3.x;       \
    acc.y += xv.x*w0.y + xv.y*w1.y + xv.z*w2.y + xv.w*w3.y;       \
    acc.z += xv.x*w0.z + xv.y*w1.z + xv.z*w2.z + xv.w*w3.z;       \
    acc.w += xv.x*w0.w + xv.y*w1.w + xv.z*w2.w + xv.w*w3.w;

__global__ __launch_bounds__(256, 2)
void k_gemm(float* xio, const float* __restrict__ W,
            const float* __restrict__ betaP, int n_rows) {
    __shared__ float Wt[DD * DD];   // Wt[d*128 + c] = W[c*128 + d]
    const int tid = threadIdx.x;
    {
        int c = (tid & 31) << 2;
        int dsel = tid >> 5;
        for (int p = 0; p < 4; ++p) {
            int d = ((p << 3) + dsel) << 2;
            float4 r0 = *(const float4*)(W + (c + 0) * DD + d);
            float4 r1 = *(const float4*)(W + (c + 1) * DD + d);
            float4 r2 = *(const float4*)(W + (c + 2) * DD + d);
            float4 r3 = *(const float4*)(W + (c + 3) * DD + d);
            *(float4*)(Wt + (d + 0) * DD + c) = make_float4(r0.x, r1.x, r2.x, r3.x);
            *(float4*)(Wt + (d + 1) * DD + c) = make_float4(r0.y, r1.y, r2.y, r3.y);
            *(float4*)(Wt + (d + 2) * DD + c) = make_float4(r0.z, r1.z, r2.z, r3.z);
            *(float4*)(Wt + (d + 3) * DD + c) = make_float4(r0.w, r1.w, r2.w, r3.w);
        }
    }
    __syncthreads();

    const float b  = betaP[0];
    const float ib = 1.0f - b;
    const int t4 = (tid & 31) << 2;
    const int rg = tid >> 5;
    const int ntiles = n_rows >> 5;

    for (int tile = blockIdx.x; tile < ntiles; tile += gridDim.x) {
        const int row0 = (tile << 5) + (rg << 2);
        const float* xr = xio + (size_t)row0 * DD;
        float4 a0 = {0,0,0,0}, a1 = {0,0,0,0}, a2 = {0,0,0,0}, a3 = {0,0,0,0};
        #pragma unroll 8
        for (int d = 0; d < DD; d += 4) {
            float4 w0 = *(const float4*)(Wt + (d + 0) * DD + t4);
            float4 w1 = *(const float4*)(Wt + (d + 1) * DD + t4);
            float4 w2 = *(const float4*)(Wt + (d + 2) * DD + t4);
            float4 w3 = *(const float4*)(Wt + (d + 3) * DD + t4);
            float4 x0 = *(const float4*)(xr + 0 * DD + d);
            float4 x1 = *(const float4*)(xr + 1 * DD + d);
            float4 x2 = *(const float4*)(xr + 2 * DD + d);
            float4 x3 = *(const float4*)(xr + 3 * DD + d);
            ROWFMA(a0, x0)
            ROWFMA(a1, x1)
            ROWFMA(a2, x2)
            ROWFMA(a3, x3)
        }
        {
            float4 e0 = *(const float4*)(xr + 0 * DD + t4);
            float4 e1 = *(const float4*)(xr + 1 * DD + t4);
            float4 e2 = *(const float4*)(xr + 2 * DD + t4);
            float4 e3 = *(const float4*)(xr + 3 * DD + t4);
            float4 o;
            float* wr = xio + (size_t)row0 * DD;
            o.x = ib*e0.x + b*a0.x; o.y = ib*e0.y + b*a0.y;
            o.z = ib*e0.z + b*a0.z; o.w = ib*e0.w + b*a0.w;
            *(float4*)(wr + 0 * DD + t4) = o;
            o.x = ib*e1.x + b*a1.x; o.y = ib*e1.y + b*a1.y;
            o.z = ib*e1.z + b*a1.z; o.w = ib*e1.w + b*a1.w;
            *(float4*)(wr + 1 * DD + t4) = o;
            o.x = ib*e2.x + b*a2.x; o.y = ib*e2.y + b*a2.y;
            o.z = ib*e2.z + b*a2.z; o.w = ib*e2.w + b*a2.w;
            *(float4*)(wr + 2 * DD + t4) = o;
            o.x = ib*e3.x + b*a3.x; o.y = ib*e3.y + b*a3.y;
            o.z = ib*e3.z + b*a3.z; o.w = ib*e3.w + b*a3.w;
            *(float4*)(wr + 3 * DD + t4) = o;
        }
    }
}

// ---------------------------------------------------------------------------
extern "C" void kernel_launch(void* const* d_in, const int* in_sizes, int n_in,
                              void* d_out, int out_size, void* d_ws, size_t ws_size,
                              hipStream_t stream) {
    const float* X     = (const float*)d_in[0];
    const float* X0    = (const float*)d_in[1];
    const float* degE  = (const float*)d_in[2];
    const float* degV  = (const float*)d_in[3];
    const float* alpha = (const float*)d_in[4];
    const float* beta  = (const float*)d_in[5];
    const float* W     = (const float*)d_in[6];
    const int*   g1s   = (const int*)d_in[7];
    const int*   g1d   = (const int*)d_in[8];
    const int*   g2s   = (const int*)d_in[9];
    const int*   g2d   = (const int*)d_in[10];
    float* out = (float*)d_out;

    const int n_nodes = in_sizes[3];        // 100000 (degV count)
    const int n_edges = in_sizes[2];        // 20000  (degE count)
    const int nnz     = in_sizes[7];        // 800000

    // --- workspace layout (4-byte units) ---
    int*   wsi   = (int*)d_ws;
    float* Xe    = (float*)d_ws;                       // [E*128] floats
    size_t o     = (size_t)n_edges * DD;               // 2,560,000
    int*   cnt1  = wsi + o;          o += n_edges;     // zeroed
    int*   cur1  = wsi + o;          o += n_edges;     // zeroed
    int*   cnt2  = wsi + o;          o += n_nodes;     // zeroed
    int*   cur2  = wsi + o;          o += n_nodes;     // zeroed
    int*   off1  = wsi + o;          o += n_edges + 1;
    int*   off2  = wsi + o;          o += n_nodes + 1;
    int*   srcs1 = wsi + o;          o += nnz;
    int*   srcs2 = wsi + o;          o += nnz;
    int*   bsum  = wsi + o;          o += 64;

    // zero the four counter arrays in one shot (contiguous)
    hipMemsetAsync(cnt1, 0, (size_t)(2 * n_edges + 2 * n_nodes) * sizeof(int), stream);

    const int nnzb = (nnz + 255) / 256;

    // ---- CSR for g1 (keyed by hyperedge dst) ----
    k_hist<<<nnzb, 256, 0, stream>>>(g1d, cnt1, nnz);
    {
        int nb = (n_edges + SCAN_CHUNK - 1) / SCAN_CHUNK;          // 10
        k_scan_blocks<<<nb, 256, 0, stream>>>(cnt1, off1, bsum, n_edges);
        k_scan_top<<<1, 64, 0, stream>>>(bsum, nb);
        k_scan_add<<<(n_edges + 255) / 256, 256, 0, stream>>>(off1, bsum, n_edges, nnz);
    }
    k_fill<<<nnzb, 256, 0, stream>>>(g1d, g1s, off1, cur1, srcs1, nnz);

    // ---- CSR for g2 (keyed by node dst) ----
    k_hist<<<nnzb, 256, 0, stream>>>(g2d, cnt2, nnz);
    {
        int nb = (n_nodes + SCAN_CHUNK - 1) / SCAN_CHUNK;          // 49
        k_scan_blocks<<<nb, 256, 0, stream>>>(cnt2, off2, bsum, n_nodes);
        k_scan_top<<<1, 64, 0, stream>>>(bsum, nb);
        k_scan_add<<<(n_nodes + 255) / 256, 256, 0, stream>>>(off2, bsum, n_nodes, nnz);
    }
    k_fill<<<nnzb, 256, 0, stream>>>(g2d, g2s, off2, cur2, srcs2, nnz);

    // ---- gather phases (no fp32 atomics anywhere) ----
    k_edge_gather<<<(n_edges * 32 + 255) / 256, 256, 0, stream>>>(
        X, off1, srcs1, degE, Xe, n_edges);
    k_node_gather<<<(n_nodes * 32 + 255) / 256, 256, 0, stream>>>(
        Xe, off2, srcs2, degV, X0, alpha, out, n_nodes);

    // ---- out = (1-b)*Xi + b*(Xi @ W^T), in place ----
    k_gemm<<<512, 256, 0, stream>>>(out, W, beta, n_nodes);
}

// Round 3
// 480.749 us; speedup vs baseline: 6.0220x; 1.1104x over previous
//
#include <hip/hip_runtime.h>

#define DD 128
#define SCAN_CHUNK 2048   // 256 threads x 8 elements per scan block

// ---------------------------------------------------------------------------
// Fused CSR build for both graphs:
//   hist -> block scan -> top scan -> add -> fill   (5 dispatches total)
// ---------------------------------------------------------------------------
__global__ __launch_bounds__(256)
void k_hist2(const int* __restrict__ g1d, const int* __restrict__ g2d,
             int* __restrict__ cnt1, int* __restrict__ cnt2, int nnz) {
    int i = blockIdx.x * 256 + threadIdx.x;
    if (i < nnz) {
        atomicAdd(&cnt1[g1d[i]], 1);
    } else {
        i -= nnz;
        if (i < nnz) atomicAdd(&cnt2[g2d[i]], 1);
    }
}

__global__ __launch_bounds__(256)
void k_scan_blocks2(const int* __restrict__ cnt1, int* __restrict__ off1,
                    const int* __restrict__ cnt2, int* __restrict__ off2,
                    int* __restrict__ bsum, int n1, int n2, int nb1) {
    __shared__ int sh[256];
    const int tid = threadIdx.x;
    const int b = blockIdx.x;
    const int* cnt; int* off; int* bs; int n; int lb;
    if (b < nb1) { cnt = cnt1; off = off1; bs = bsum;      n = n1; lb = b; }
    else         { cnt = cnt2; off = off2; bs = bsum + 64; n = n2; lb = b - nb1; }

    const int base = lb * SCAN_CHUNK + tid * 8;
    int v[8];
    int s = 0;
    #pragma unroll
    for (int j = 0; j < 8; ++j) {
        int idx = base + j;
        v[j] = (idx < n) ? cnt[idx] : 0;
        s += v[j];
    }
    sh[tid] = s;
    __syncthreads();
    for (int d = 1; d < 256; d <<= 1) {
        int y = (tid >= d) ? sh[tid - d] : 0;
        __syncthreads();
        sh[tid] += y;
        __syncthreads();
    }
    int incl = sh[tid];
    int run = incl - s;
    #pragma unroll
    for (int j = 0; j < 8; ++j) {
        int idx = base + j;
        if (idx < n) off[idx] = run;
        run += v[j];
    }
    if (tid == 255) bs[lb] = incl;
}

__global__ void k_scan_top2(int* __restrict__ bsum, int nb1, int nb2) {
    if (threadIdx.x == 0) {
        int run = 0;
        for (int i = 0; i < nb1; ++i) { int t = bsum[i]; bsum[i] = run; run += t; }
    } else if (threadIdx.x == 1) {
        int run = 0;
        for (int i = 0; i < nb2; ++i) { int t = bsum[64 + i]; bsum[64 + i] = run; run += t; }
    }
}

__global__ __launch_bounds__(256)
void k_scan_add2(int* __restrict__ off1, int* __restrict__ off2,
                 const int* __restrict__ bsum, int n1, int n2, int nnz) {
    int gid = blockIdx.x * 256 + threadIdx.x;
    if (gid < n1) {
        off1[gid] += bsum[gid >> 11];            // SCAN_CHUNK == 2048
    } else {
        int g = gid - n1;
        if (g < n2) off2[g] += bsum[64 + (g >> 11)];
    }
    if (gid == 0) { off1[n1] = nnz; off2[n2] = nnz; }
}

__global__ __launch_bounds__(256)
void k_fill2(const int* __restrict__ g1d, const int* __restrict__ g1s,
             const int* __restrict__ off1, int* __restrict__ cur1, int* __restrict__ srcs1,
             const int* __restrict__ g2d, const int* __restrict__ g2s,
             const int* __restrict__ off2, int* __restrict__ cur2, int* __restrict__ srcs2,
             int nnz) {
    int i = blockIdx.x * 256 + threadIdx.x;
    if (i < nnz) {
        int d = g1d[i];
        int p = atomicAdd(&cur1[d], 1);
        srcs1[off1[d] + p] = g1s[i];
    } else {
        i -= nnz;
        if (i < nnz) {
            int d = g2d[i];
            int p = atomicAdd(&cur2[d], 1);
            srcs2[off2[d] + p] = g2s[i];
        }
    }
}

// ---------------------------------------------------------------------------
// k_edge_gather: Xe[e] = degE[e] * sum_{j in seg(e)} X[srcs1[j]]
// half-wave (32 lanes) per edge row; float4 per lane; 4-way unrolled
// (4 independent row loads in flight per lane -> hides gather latency).
// ---------------------------------------------------------------------------
__global__ __launch_bounds__(256)
void k_edge_gather(const float* __restrict__ X, const int* __restrict__ off,
                   const int* __restrict__ srcs, const float* __restrict__ degE,
                   float* __restrict__ Xe, int n_edges) {
    int gid = blockIdx.x * 256 + threadIdx.x;
    int e = gid >> 5;
    if (e >= n_edges) return;
    int k = (gid & 31) << 2;
    int beg = off[e], end = off[e + 1];
    float4 acc0 = {0, 0, 0, 0}, acc1 = {0, 0, 0, 0};
    int j = beg;
    for (; j + 4 <= end; j += 4) {
        int s0 = srcs[j + 0];
        int s1 = srcs[j + 1];
        int s2 = srcs[j + 2];
        int s3 = srcs[j + 3];
        float4 v0 = *(const float4*)(X + (size_t)s0 * DD + k);
        float4 v1 = *(const float4*)(X + (size_t)s1 * DD + k);
        float4 v2 = *(const float4*)(X + (size_t)s2 * DD + k);
        float4 v3 = *(const float4*)(X + (size_t)s3 * DD + k);
        acc0.x += v0.x; acc0.y += v0.y; acc0.z += v0.z; acc0.w += v0.w;
        acc1.x += v1.x; acc1.y += v1.y; acc1.z += v1.z; acc1.w += v1.w;
        acc0.x += v2.x; acc0.y += v2.y; acc0.z += v2.z; acc0.w += v2.w;
        acc1.x += v3.x; acc1.y += v3.y; acc1.z += v3.z; acc1.w += v3.w;
    }
    for (; j < end; ++j) {
        int s = srcs[j];
        float4 v = *(const float4*)(X + (size_t)s * DD + k);
        acc0.x += v.x; acc0.y += v.y; acc0.z += v.z; acc0.w += v.w;
    }
    float f = degE[e];
    float4 o;
    o.x = f * (acc0.x + acc1.x);
    o.y = f * (acc0.y + acc1.y);
    o.z = f * (acc0.z + acc1.z);
    o.w = f * (acc0.w + acc1.w);
    *(float4*)(Xe + (size_t)e * DD + k) = o;
}

// ---------------------------------------------------------------------------
// k_node_gather: Xi[v] = (1-a)*degV[v] * sum_{j in seg(v)} Xe[srcs2[j]] + a*X0[v]
// writes Xi into d_out; 4-way unrolled like edge gather.
// ---------------------------------------------------------------------------
__global__ __launch_bounds__(256)
void k_node_gather(const float* __restrict__ Xe, const int* __restrict__ off,
                   const int* __restrict__ srcs, const float* __restrict__ degV,
                   const float* __restrict__ X0, const float* __restrict__ alphaP,
                   float* __restrict__ Xi, int n_nodes) {
    int gid = blockIdx.x * 256 + threadIdx.x;
    int v = gid >> 5;
    if (v >= n_nodes) return;
    int k = (gid & 31) << 2;
    int beg = off[v], end = off[v + 1];
    float4 acc0 = {0, 0, 0, 0}, acc1 = {0, 0, 0, 0};
    int j = beg;
    for (; j + 4 <= end; j += 4) {
        int s0 = srcs[j + 0];
        int s1 = srcs[j + 1];
        int s2 = srcs[j + 2];
        int s3 = srcs[j + 3];
        float4 v0 = *(const float4*)(Xe + (size_t)s0 * DD + k);
        float4 v1 = *(const float4*)(Xe + (size_t)s1 * DD + k);
        float4 v2 = *(const float4*)(Xe + (size_t)s2 * DD + k);
        float4 v3 = *(const float4*)(Xe + (size_t)s3 * DD + k);
        acc0.x += v0.x; acc0.y += v0.y; acc0.z += v0.z; acc0.w += v0.w;
        acc1.x += v1.x; acc1.y += v1.y; acc1.z += v1.z; acc1.w += v1.w;
        acc0.x += v2.x; acc0.y += v2.y; acc0.z += v2.z; acc0.w += v2.w;
        acc1.x += v3.x; acc1.y += v3.y; acc1.z += v3.z; acc1.w += v3.w;
    }
    for (; j < end; ++j) {
        int s = srcs[j];
        float4 x = *(const float4*)(Xe + (size_t)s * DD + k);
        acc0.x += x.x; acc0.y += x.y; acc0.z += x.z; acc0.w += x.w;
    }
    float a = alphaP[0];
    float f = (1.0f - a) * degV[v];
    float4 x0 = *(const float4*)(X0 + (size_t)v * DD + k);
    float4 o;
    o.x = f * (acc0.x + acc1.x) + a * x0.x;
    o.y = f * (acc0.y + acc1.y) + a * x0.y;
    o.z = f * (acc0.z + acc1.z) + a * x0.z;
    o.w = f * (acc0.w + acc1.w) + a * x0.w;
    *(float4*)(Xi + (size_t)v * DD + k) = o;
}

// ---------------------------------------------------------------------------
// k_gemm: out = (1-b)*Xi + b * (Xi @ W^T), in place (xio = Xi = out).
// W transposed into 64 KB static LDS; 4x4 register tile per thread.
// In-place safe: each row read/written only by one half-wave (program order).
// ---------------------------------------------------------------------------
#define ROWFMA(acc, xv)                                           \
    acc.x += xv.x*w0.x + xv.y*w1.x + xv.z*w2.x + xv.w*w3.x;       \
    acc.y += xv.x*w0.y + xv.y*w1.y + xv.z*w2.y + xv.w*w3.y;       \
    acc.z += xv.x*w0.z + xv.y*w1.z + xv.z*w2.z + xv.w*w3.z;       \
    acc.w += xv.x*w0.w + xv.y*w1.w + xv.z*w2.w + xv.w*w3.w;

__global__ __launch_bounds__(256, 2)
void k_gemm(float* xio, const float* __restrict__ W,
            const float* __restrict__ betaP, int n_rows) {
    __shared__ float Wt[DD * DD];   // Wt[d*128 + c] = W[c*128 + d]
    const int tid = threadIdx.x;
    {
        int c = (tid & 31) << 2;
        int dsel = tid >> 5;
        for (int p = 0; p < 4; ++p) {
            int d = ((p << 3) + dsel) << 2;
            float4 r0 = *(const float4*)(W + (c + 0) * DD + d);
            float4 r1 = *(const float4*)(W + (c + 1) * DD + d);
            float4 r2 = *(const float4*)(W + (c + 2) * DD + d);
            float4 r3 = *(const float4*)(W + (c + 3) * DD + d);
            *(float4*)(Wt + (d + 0) * DD + c) = make_float4(r0.x, r1.x, r2.x, r3.x);
            *(float4*)(Wt + (d + 1) * DD + c) = make_float4(r0.y, r1.y, r2.y, r3.y);
            *(float4*)(Wt + (d + 2) * DD + c) = make_float4(r0.z, r1.z, r2.z, r3.z);
            *(float4*)(Wt + (d + 3) * DD + c) = make_float4(r0.w, r1.w, r2.w, r3.w);
        }
    }
    __syncthreads();

    const float b  = betaP[0];
    const float ib = 1.0f - b;
    const int t4 = (tid & 31) << 2;
    const int rg = tid >> 5;
    const int ntiles = n_rows >> 5;

    for (int tile = blockIdx.x; tile < ntiles; tile += gridDim.x) {
        const int row0 = (tile << 5) + (rg << 2);
        const float* xr = xio + (size_t)row0 * DD;
        float4 a0 = {0,0,0,0}, a1 = {0,0,0,0}, a2 = {0,0,0,0}, a3 = {0,0,0,0};
        #pragma unroll 8
        for (int d = 0; d < DD; d += 4) {
            float4 w0 = *(const float4*)(Wt + (d + 0) * DD + t4);
            float4 w1 = *(const float4*)(Wt + (d + 1) * DD + t4);
            float4 w2 = *(const float4*)(Wt + (d + 2) * DD + t4);
            float4 w3 = *(const float4*)(Wt + (d + 3) * DD + t4);
            float4 x0 = *(const float4*)(xr + 0 * DD + d);
            float4 x1 = *(const float4*)(xr + 1 * DD + d);
            float4 x2 = *(const float4*)(xr + 2 * DD + d);
            float4 x3 = *(const float4*)(xr + 3 * DD + d);
            ROWFMA(a0, x0)
            ROWFMA(a1, x1)
            ROWFMA(a2, x2)
            ROWFMA(a3, x3)
        }
        {
            float4 e0 = *(const float4*)(xr + 0 * DD + t4);
            float4 e1 = *(const float4*)(xr + 1 * DD + t4);
            float4 e2 = *(const float4*)(xr + 2 * DD + t4);
            float4 e3 = *(const float4*)(xr + 3 * DD + t4);
            float4 o;
            float* wr = xio + (size_t)row0 * DD;
            o.x = ib*e0.x + b*a0.x; o.y = ib*e0.y + b*a0.y;
            o.z = ib*e0.z + b*a0.z; o.w = ib*e0.w + b*a0.w;
            *(float4*)(wr + 0 * DD + t4) = o;
            o.x = ib*e1.x + b*a1.x; o.y = ib*e1.y + b*a1.y;
            o.z = ib*e1.z + b*a1.z; o.w = ib*e1.w + b*a1.w;
            *(float4*)(wr + 1 * DD + t4) = o;
            o.x = ib*e2.x + b*a2.x; o.y = ib*e2.y + b*a2.y;
            o.z = ib*e2.z + b*a2.z; o.w = ib*e2.w + b*a2.w;
            *(float4*)(wr + 2 * DD + t4) = o;
            o.x = ib*e3.x + b*a3.x; o.y = ib*e3.y + b*a3.y;
            o.z = ib*e3.z + b*a3.z; o.w = ib*e3.w + b*a3.w;
            *(float4*)(wr + 3 * DD + t4) = o;
        }
    }
}

// ---------------------------------------------------------------------------
extern "C" void kernel_launch(void* const* d_in, const int* in_sizes, int n_in,
                              void* d_out, int out_size, void* d_ws, size_t ws_size,
                              hipStream_t stream) {
    const float* X     = (const float*)d_in[0];
    const float* X0    = (const float*)d_in[1];
    const float* degE  = (const float*)d_in[2];
    const float* degV  = (const float*)d_in[3];
    const float* alpha = (const float*)d_in[4];
    const float* beta  = (const float*)d_in[5];
    const float* W     = (const float*)d_in[6];
    const int*   g1s   = (const int*)d_in[7];
    const int*   g1d   = (const int*)d_in[8];
    const int*   g2s   = (const int*)d_in[9];
    const int*   g2d   = (const int*)d_in[10];
    float* out = (float*)d_out;

    const int n_nodes = in_sizes[3];        // 100000 (degV count)
    const int n_edges = in_sizes[2];        // 20000  (degE count)
    const int nnz     = in_sizes[7];        // 800000

    // --- workspace layout (4-byte units) ---
    int*   wsi   = (int*)d_ws;
    float* Xe    = (float*)d_ws;                       // [E*128] floats
    size_t o     = (size_t)n_edges * DD;
    int*   cnt1  = wsi + o;          o += n_edges;     // zeroed
    int*   cur1  = wsi + o;          o += n_edges;     // zeroed
    int*   cnt2  = wsi + o;          o += n_nodes;     // zeroed
    int*   cur2  = wsi + o;          o += n_nodes;     // zeroed
    int*   off1  = wsi + o;          o += n_edges + 1;
    int*   off2  = wsi + o;          o += n_nodes + 1;
    int*   srcs1 = wsi + o;          o += nnz;
    int*   srcs2 = wsi + o;          o += nnz;
    int*   bsum  = wsi + o;          o += 128;

    // zero the four counter arrays in one shot (contiguous)
    hipMemsetAsync(cnt1, 0, (size_t)(2 * n_edges + 2 * n_nodes) * sizeof(int), stream);

    const int nb1 = (n_edges + SCAN_CHUNK - 1) / SCAN_CHUNK;   // 10
    const int nb2 = (n_nodes + SCAN_CHUNK - 1) / SCAN_CHUNK;   // 49
    const int dblb = (2 * nnz + 255) / 256;

    // ---- fused CSR build for g1 (dst=hyperedge) and g2 (dst=node) ----
    k_hist2<<<dblb, 256, 0, stream>>>(g1d, g2d, cnt1, cnt2, nnz);
    k_scan_blocks2<<<nb1 + nb2, 256, 0, stream>>>(cnt1, off1, cnt2, off2, bsum,
                                                  n_edges, n_nodes, nb1);
    k_scan_top2<<<1, 64, 0, stream>>>(bsum, nb1, nb2);
    k_scan_add2<<<(n_edges + n_nodes + 255) / 256, 256, 0, stream>>>(
        off1, off2, bsum, n_edges, n_nodes, nnz);
    k_fill2<<<dblb, 256, 0, stream>>>(g1d, g1s, off1, cur1, srcs1,
                                      g2d, g2s, off2, cur2, srcs2, nnz);

    // ---- gather phases (no fp32 atomics anywhere) ----
    k_edge_gather<<<(n_edges * 32 + 255) / 256, 256, 0, stream>>>(
        X, off1, srcs1, degE, Xe, n_edges);
    k_node_gather<<<(n_nodes * 32 + 255) / 256, 256, 0, stream>>>(
        Xe, off2, srcs2, degV, X0, alpha, out, n_nodes);

    // ---- out = (1-b)*Xi + b*(Xi @ W^T), in place ----
    k_gemm<<<512, 256, 0, stream>>>(out, W, beta, n_nodes);
}

// Round 4
// 430.538 us; speedup vs baseline: 6.7243x; 1.1166x over previous
//
#include <hip/hip_runtime.h>

#define DD 128
#define SCAN_CHUNK 2048   // 256 threads x 8 elements per scan block

// ---------------------------------------------------------------------------
// k_hist2: histogram both graphs AND capture each element's rank within its
// destination bucket (the atomicAdd return value). rank store is coalesced.
// 4 elements per thread (int4) -> 4 independent atomic chains per lane.
// ---------------------------------------------------------------------------
__global__ __launch_bounds__(256)
void k_hist2(const int* __restrict__ g1d, const int* __restrict__ g2d,
             int* __restrict__ cnt1, int* __restrict__ cnt2,
             int* __restrict__ rank1, int* __restrict__ rank2,
             int nnz, int nq) {
    int gid = blockIdx.x * 256 + threadIdx.x;
    const int* dst; int* cnt; int* rank; int q;
    if (gid < nq) { dst = g1d; cnt = cnt1; rank = rank1; q = gid; }
    else {
        q = gid - nq;
        if (q >= nq) return;
        dst = g2d; cnt = cnt2; rank = rank2;
    }
    int i = q << 2;
    if (i + 4 <= nnz) {
        int4 d = *(const int4*)(dst + i);
        int r0 = atomicAdd(&cnt[d.x], 1);
        int r1 = atomicAdd(&cnt[d.y], 1);
        int r2 = atomicAdd(&cnt[d.z], 1);
        int r3 = atomicAdd(&cnt[d.w], 1);
        *(int4*)(rank + i) = make_int4(r0, r1, r2, r3);
    } else {
        for (; i < nnz; ++i) rank[i] = atomicAdd(&cnt[dst[i]], 1);
    }
}

__global__ __launch_bounds__(256)
void k_scan_blocks2(const int* __restrict__ cnt1, int* __restrict__ off1,
                    const int* __restrict__ cnt2, int* __restrict__ off2,
                    int* __restrict__ bsum, int n1, int n2, int nb1) {
    __shared__ int sh[256];
    const int tid = threadIdx.x;
    const int b = blockIdx.x;
    const int* cnt; int* off; int* bs; int n; int lb;
    if (b < nb1) { cnt = cnt1; off = off1; bs = bsum;      n = n1; lb = b; }
    else         { cnt = cnt2; off = off2; bs = bsum + 64; n = n2; lb = b - nb1; }

    const int base = lb * SCAN_CHUNK + tid * 8;
    int v[8];
    int s = 0;
    #pragma unroll
    for (int j = 0; j < 8; ++j) {
        int idx = base + j;
        v[j] = (idx < n) ? cnt[idx] : 0;
        s += v[j];
    }
    sh[tid] = s;
    __syncthreads();
    for (int d = 1; d < 256; d <<= 1) {
        int y = (tid >= d) ? sh[tid - d] : 0;
        __syncthreads();
        sh[tid] += y;
        __syncthreads();
    }
    int incl = sh[tid];
    int run = incl - s;
    #pragma unroll
    for (int j = 0; j < 8; ++j) {
        int idx = base + j;
        if (idx < n) off[idx] = run;
        run += v[j];
    }
    if (tid == 255) bs[lb] = incl;
}

__global__ void k_scan_top2(int* __restrict__ bsum, int nb1, int nb2) {
    if (threadIdx.x == 0) {
        int run = 0;
        for (int i = 0; i < nb1; ++i) { int t = bsum[i]; bsum[i] = run; run += t; }
    } else if (threadIdx.x == 1) {
        int run = 0;
        for (int i = 0; i < nb2; ++i) { int t = bsum[64 + i]; bsum[64 + i] = run; run += t; }
    }
}

__global__ __launch_bounds__(256)
void k_scan_add2(int* __restrict__ off1, int* __restrict__ off2,
                 const int* __restrict__ bsum, int n1, int n2, int nnz) {
    int gid = blockIdx.x * 256 + threadIdx.x;
    if (gid < n1) {
        off1[gid] += bsum[gid >> 11];            // SCAN_CHUNK == 2048
    } else {
        int g = gid - n1;
        if (g < n2) off2[g] += bsum[64 + (g >> 11)];
    }
    if (gid == 0) { off1[n1] = nnz; off2[n2] = nnz; }
}

// ---------------------------------------------------------------------------
// k_fill2: srcs[off[d] + rank[i]] = src[i]. No atomics — rank precomputed in
// k_hist2. 4 elements per thread: 4 independent off-loads then 4 scattered
// stores (fire-and-forget).
// ---------------------------------------------------------------------------
__global__ __launch_bounds__(256)
void k_fill2(const int* __restrict__ g1d, const int* __restrict__ g1s,
             const int* __restrict__ off1, const int* __restrict__ rank1,
             int* __restrict__ srcs1,
             const int* __restrict__ g2d, const int* __restrict__ g2s,
             const int* __restrict__ off2, const int* __restrict__ rank2,
             int* __restrict__ srcs2,
             int nnz, int nq) {
    int gid = blockIdx.x * 256 + threadIdx.x;
    const int* dst; const int* src; const int* off; const int* rank; int* out; int q;
    if (gid < nq) { dst = g1d; src = g1s; off = off1; rank = rank1; out = srcs1; q = gid; }
    else {
        q = gid - nq;
        if (q >= nq) return;
        dst = g2d; src = g2s; off = off2; rank = rank2; out = srcs2;
    }
    int i = q << 2;
    if (i + 4 <= nnz) {
        int4 d = *(const int4*)(dst + i);
        int4 s = *(const int4*)(src + i);
        int4 r = *(const int4*)(rank + i);
        int o0 = off[d.x];
        int o1 = off[d.y];
        int o2 = off[d.z];
        int o3 = off[d.w];
        out[o0 + r.x] = s.x;
        out[o1 + r.y] = s.y;
        out[o2 + r.z] = s.z;
        out[o3 + r.w] = s.w;
    } else {
        for (; i < nnz; ++i) out[off[dst[i]] + rank[i]] = src[i];
    }
}

// ---------------------------------------------------------------------------
// k_edge_gather: Xe[e] = degE[e] * sum_{j in seg(e)} X[srcs1[j]]
// half-wave (32 lanes) per edge row; float4 per lane; 8-way unrolled
// (8 independent row loads in flight per lane -> hides gather latency).
// ---------------------------------------------------------------------------
__global__ __launch_bounds__(256)
void k_edge_gather(const float* __restrict__ X, const int* __restrict__ off,
                   const int* __restrict__ srcs, const float* __restrict__ degE,
                   float* __restrict__ Xe, int n_edges) {
    int gid = blockIdx.x * 256 + threadIdx.x;
    int e = gid >> 5;
    if (e >= n_edges) return;
    int k = (gid & 31) << 2;
    int beg = off[e], end = off[e + 1];
    float4 acc0 = {0, 0, 0, 0}, acc1 = {0, 0, 0, 0};
    float4 acc2 = {0, 0, 0, 0}, acc3 = {0, 0, 0, 0};
    int j = beg;
    for (; j + 8 <= end; j += 8) {
        int s0 = srcs[j + 0];
        int s1 = srcs[j + 1];
        int s2 = srcs[j + 2];
        int s3 = srcs[j + 3];
        int s4 = srcs[j + 4];
        int s5 = srcs[j + 5];
        int s6 = srcs[j + 6];
        int s7 = srcs[j + 7];
        float4 v0 = *(const float4*)(X + (size_t)s0 * DD + k);
        float4 v1 = *(const float4*)(X + (size_t)s1 * DD + k);
        float4 v2 = *(const float4*)(X + (size_t)s2 * DD + k);
        float4 v3 = *(const float4*)(X + (size_t)s3 * DD + k);
        float4 v4 = *(const float4*)(X + (size_t)s4 * DD + k);
        float4 v5 = *(const float4*)(X + (size_t)s5 * DD + k);
        float4 v6 = *(const float4*)(X + (size_t)s6 * DD + k);
        float4 v7 = *(const float4*)(X + (size_t)s7 * DD + k);
        acc0.x += v0.x; acc0.y += v0.y; acc0.z += v0.z; acc0.w += v0.w;
        acc1.x += v1.x; acc1.y += v1.y; acc1.z += v1.z; acc1.w += v1.w;
        acc2.x += v2.x; acc2.y += v2.y; acc2.z += v2.z; acc2.w += v2.w;
        acc3.x += v3.x; acc3.y += v3.y; acc3.z += v3.z; acc3.w += v3.w;
        acc0.x += v4.x; acc0.y += v4.y; acc0.z += v4.z; acc0.w += v4.w;
        acc1.x += v5.x; acc1.y += v5.y; acc1.z += v5.z; acc1.w += v5.w;
        acc2.x += v6.x; acc2.y += v6.y; acc2.z += v6.z; acc2.w += v6.w;
        acc3.x += v7.x; acc3.y += v7.y; acc3.z += v7.z; acc3.w += v7.w;
    }
    for (; j < end; ++j) {
        int s = srcs[j];
        float4 v = *(const float4*)(X + (size_t)s * DD + k);
        acc0.x += v.x; acc0.y += v.y; acc0.z += v.z; acc0.w += v.w;
    }
    float f = degE[e];
    float4 o;
    o.x = f * ((acc0.x + acc1.x) + (acc2.x + acc3.x));
    o.y = f * ((acc0.y + acc1.y) + (acc2.y + acc3.y));
    o.z = f * ((acc0.z + acc1.z) + (acc2.z + acc3.z));
    o.w = f * ((acc0.w + acc1.w) + (acc2.w + acc3.w));
    *(float4*)(Xe + (size_t)e * DD + k) = o;
}

// ---------------------------------------------------------------------------
// k_node_gather: Xi[v] = (1-a)*degV[v] * sum_{j in seg(v)} Xe[srcs2[j]] + a*X0[v]
// writes Xi into d_out; 4-way unrolled (avg segment 8).
// ---------------------------------------------------------------------------
__global__ __launch_bounds__(256)
void k_node_gather(const float* __restrict__ Xe, const int* __restrict__ off,
                   const int* __restrict__ srcs, const float* __restrict__ degV,
                   const float* __restrict__ X0, const float* __restrict__ alphaP,
                   float* __restrict__ Xi, int n_nodes) {
    int gid = blockIdx.x * 256 + threadIdx.x;
    int v = gid >> 5;
    if (v >= n_nodes) return;
    int k = (gid & 31) << 2;
    int beg = off[v], end = off[v + 1];
    float4 acc0 = {0, 0, 0, 0}, acc1 = {0, 0, 0, 0};
    int j = beg;
    for (; j + 4 <= end; j += 4) {
        int s0 = srcs[j + 0];
        int s1 = srcs[j + 1];
        int s2 = srcs[j + 2];
        int s3 = srcs[j + 3];
        float4 v0 = *(const float4*)(Xe + (size_t)s0 * DD + k);
        float4 v1 = *(const float4*)(Xe + (size_t)s1 * DD + k);
        float4 v2 = *(const float4*)(Xe + (size_t)s2 * DD + k);
        float4 v3 = *(const float4*)(Xe + (size_t)s3 * DD + k);
        acc0.x += v0.x; acc0.y += v0.y; acc0.z += v0.z; acc0.w += v0.w;
        acc1.x += v1.x; acc1.y += v1.y; acc1.z += v1.z; acc1.w += v1.w;
        acc0.x += v2.x; acc0.y += v2.y; acc0.z += v2.z; acc0.w += v2.w;
        acc1.x += v3.x; acc1.y += v3.y; acc1.z += v3.z; acc1.w += v3.w;
    }
    for (; j < end; ++j) {
        int s = srcs[j];
        float4 x = *(const float4*)(Xe + (size_t)s * DD + k);
        acc0.x += x.x; acc0.y += x.y; acc0.z += x.z; acc0.w += x.w;
    }
    float a = alphaP[0];
    float f = (1.0f - a) * degV[v];
    float4 x0 = *(const float4*)(X0 + (size_t)v * DD + k);
    float4 o;
    o.x = f * (acc0.x + acc1.x) + a * x0.x;
    o.y = f * (acc0.y + acc1.y) + a * x0.y;
    o.z = f * (acc0.z + acc1.z) + a * x0.z;
    o.w = f * (acc0.w + acc1.w) + a * x0.w;
    *(float4*)(Xi + (size_t)v * DD + k) = o;
}

// ---------------------------------------------------------------------------
// k_gemm: out = (1-b)*Xi + b * (Xi @ W^T), in place (xio = Xi = out).
// W transposed into 64 KB static LDS; 4x4 register tile per thread.
// In-place safe: each row read/written only by one half-wave (program order).
// ---------------------------------------------------------------------------
#define ROWFMA(acc, xv)                                           \
    acc.x += xv.x*w0.x + xv.y*w1.x + xv.z*w2.x + xv.w*w3.x;       \
    acc.y += xv.x*w0.y + xv.y*w1.y + xv.z*w2.y + xv.w*w3.y;       \
    acc.z += xv.x*w0.z + xv.y*w1.z + xv.z*w2.z + xv.w*w3.z;       \
    acc.w += xv.x*w0.w + xv.y*w1.w + xv.z*w2.w + xv.w*w3.w;

__global__ __launch_bounds__(256, 2)
void k_gemm(float* xio, const float* __restrict__ W,
            const float* __restrict__ betaP, int n_rows) {
    __shared__ float Wt[DD * DD];   // Wt[d*128 + c] = W[c*128 + d]
    const int tid = threadIdx.x;
    {
        int c = (tid & 31) << 2;
        int dsel = tid >> 5;
        for (int p = 0; p < 4; ++p) {
            int d = ((p << 3) + dsel) << 2;
            float4 r0 = *(const float4*)(W + (c + 0) * DD + d);
            float4 r1 = *(const float4*)(W + (c + 1) * DD + d);
            float4 r2 = *(const float4*)(W + (c + 2) * DD + d);
            float4 r3 = *(const float4*)(W + (c + 3) * DD + d);
            *(float4*)(Wt + (d + 0) * DD + c) = make_float4(r0.x, r1.x, r2.x, r3.x);
            *(float4*)(Wt + (d + 1) * DD + c) = make_float4(r0.y, r1.y, r2.y, r3.y);
            *(float4*)(Wt + (d + 2) * DD + c) = make_float4(r0.z, r1.z, r2.z, r3.z);
            *(float4*)(Wt + (d + 3) * DD + c) = make_float4(r0.w, r1.w, r2.w, r3.w);
        }
    }
    __syncthreads();

    const float b  = betaP[0];
    const float ib = 1.0f - b;
    const int t4 = (tid & 31) << 2;
    const int rg = tid >> 5;
    const int ntiles = n_rows >> 5;

    for (int tile = blockIdx.x; tile < ntiles; tile += gridDim.x) {
        const int row0 = (tile << 5) + (rg << 2);
        const float* xr = xio + (size_t)row0 * DD;
        float4 a0 = {0,0,0,0}, a1 = {0,0,0,0}, a2 = {0,0,0,0}, a3 = {0,0,0,0};
        #pragma unroll 8
        for (int d = 0; d < DD; d += 4) {
            float4 w0 = *(const float4*)(Wt + (d + 0) * DD + t4);
            float4 w1 = *(const float4*)(Wt + (d + 1) * DD + t4);
            float4 w2 = *(const float4*)(Wt + (d + 2) * DD + t4);
            float4 w3 = *(const float4*)(Wt + (d + 3) * DD + t4);
            float4 x0 = *(const float4*)(xr + 0 * DD + d);
            float4 x1 = *(const float4*)(xr + 1 * DD + d);
            float4 x2 = *(const float4*)(xr + 2 * DD + d);
            float4 x3 = *(const float4*)(xr + 3 * DD + d);
            ROWFMA(a0, x0)
            ROWFMA(a1, x1)
            ROWFMA(a2, x2)
            ROWFMA(a3, x3)
        }
        {
            float4 e0 = *(const float4*)(xr + 0 * DD + t4);
            float4 e1 = *(const float4*)(xr + 1 * DD + t4);
            float4 e2 = *(const float4*)(xr + 2 * DD + t4);
            float4 e3 = *(const float4*)(xr + 3 * DD + t4);
            float4 o;
            float* wr = xio + (size_t)row0 * DD;
            o.x = ib*e0.x + b*a0.x; o.y = ib*e0.y + b*a0.y;
            o.z = ib*e0.z + b*a0.z; o.w = ib*e0.w + b*a0.w;
            *(float4*)(wr + 0 * DD + t4) = o;
            o.x = ib*e1.x + b*a1.x; o.y = ib*e1.y + b*a1.y;
            o.z = ib*e1.z + b*a1.z; o.w = ib*e1.w + b*a1.w;
            *(float4*)(wr + 1 * DD + t4) = o;
            o.x = ib*e2.x + b*a2.x; o.y = ib*e2.y + b*a2.y;
            o.z = ib*e2.z + b*a2.z; o.w = ib*e2.w + b*a2.w;
            *(float4*)(wr + 2 * DD + t4) = o;
            o.x = ib*e3.x + b*a3.x; o.y = ib*e3.y + b*a3.y;
            o.z = ib*e3.z + b*a3.z; o.w = ib*e3.w + b*a3.w;
            *(float4*)(wr + 3 * DD + t4) = o;
        }
    }
}

// ---------------------------------------------------------------------------
extern "C" void kernel_launch(void* const* d_in, const int* in_sizes, int n_in,
                              void* d_out, int out_size, void* d_ws, size_t ws_size,
                              hipStream_t stream) {
    const float* X     = (const float*)d_in[0];
    const float* X0    = (const float*)d_in[1];
    const float* degE  = (const float*)d_in[2];
    const float* degV  = (const float*)d_in[3];
    const float* alpha = (const float*)d_in[4];
    const float* beta  = (const float*)d_in[5];
    const float* W     = (const float*)d_in[6];
    const int*   g1s   = (const int*)d_in[7];
    const int*   g1d   = (const int*)d_in[8];
    const int*   g2s   = (const int*)d_in[9];
    const int*   g2d   = (const int*)d_in[10];
    float* out = (float*)d_out;

    const int n_nodes = in_sizes[3];        // 100000 (degV count)
    const int n_edges = in_sizes[2];        // 20000  (degE count)
    const int nnz     = in_sizes[7];        // 800000

    // --- workspace layout (4-byte units) ---
    // rank1/rank2 overlay the Xe region: ranks are dead once k_fill2 finishes,
    // and Xe is first written by k_edge_gather (later in the stream).
    int*   wsi   = (int*)d_ws;
    float* Xe    = (float*)d_ws;                       // [E*128] floats (10.24 MB)
    int*   rank1 = wsi;                                // [nnz] (overlays Xe)
    int*   rank2 = wsi + nnz;                          // [nnz] (overlays Xe)
    size_t o     = (size_t)n_edges * DD;
    int*   cnt1  = wsi + o;          o += n_edges;     // zeroed
    int*   cnt2  = wsi + o;          o += n_nodes;     // zeroed
    int*   off1  = wsi + o;          o += n_edges + 1;
    int*   off2  = wsi + o;          o += n_nodes + 1;
    int*   srcs1 = wsi + o;          o += nnz;
    int*   srcs2 = wsi + o;          o += nnz;
    int*   bsum  = wsi + o;          o += 128;

    // zero the two counter arrays in one shot (contiguous)
    hipMemsetAsync(cnt1, 0, (size_t)(n_edges + n_nodes) * sizeof(int), stream);

    const int nb1 = (n_edges + SCAN_CHUNK - 1) / SCAN_CHUNK;   // 10
    const int nb2 = (n_nodes + SCAN_CHUNK - 1) / SCAN_CHUNK;   // 49
    const int nq  = (nnz + 3) / 4;                             // quads per graph
    const int qblb = (2 * nq + 255) / 256;

    // ---- fused CSR build for g1 (dst=hyperedge) and g2 (dst=node) ----
    k_hist2<<<qblb, 256, 0, stream>>>(g1d, g2d, cnt1, cnt2, rank1, rank2, nnz, nq);
    k_scan_blocks2<<<nb1 + nb2, 256, 0, stream>>>(cnt1, off1, cnt2, off2, bsum,
                                                  n_edges, n_nodes, nb1);
    k_scan_top2<<<1, 64, 0, stream>>>(bsum, nb1, nb2);
    k_scan_add2<<<(n_edges + n_nodes + 255) / 256, 256, 0, stream>>>(
        off1, off2, bsum, n_edges, n_nodes, nnz);
    k_fill2<<<qblb, 256, 0, stream>>>(g1d, g1s, off1, rank1, srcs1,
                                      g2d, g2s, off2, rank2, srcs2, nnz, nq);

    // ---- gather phases (no fp32 atomics anywhere) ----
    k_edge_gather<<<(n_edges * 32 + 255) / 256, 256, 0, stream>>>(
        X, off1, srcs1, degE, Xe, n_edges);
    k_node_gather<<<(n_nodes * 32 + 255) / 256, 256, 0, stream>>>(
        Xe, off2, srcs2, degV, X0, alpha, out, n_nodes);

    // ---- out = (1-b)*Xi + b*(Xi @ W^T), in place ----
    k_gemm<<<512, 256, 0, stream>>>(out, W, beta, n_nodes);
}